// Round 1
// baseline (39.821 us; speedup 1.0000x reference)
//
#include <hip/hip_runtime.h>
#include <hip/hip_bf16.h>

// Problem constants (from the reference):
// T=4 tables, V=1e6 vocab, D=64 emb dim, B=4096 bags, N=81920 indices/table.
constexpr int T = 4;
constexpr int V = 1000000;
constexpr int D = 64;
constexpr int B = 4096;
constexpr int N = 81920;

// One wave (64 lanes) per bag. Wave splits into 4 row-groups x 16 lanes;
// each lane accumulates a float4 chunk (16B) of its row-group's rows, then
// a shfl_xor(16,32) reduction combines row-groups; lanes 0..15 store 256B.
__global__ __launch_bounds__(256) void embbag_kernel(
    const float* __restrict__ tables,
    const int* __restrict__ indices,
    const int* __restrict__ offsets,
    float* __restrict__ out) {
    const int gwave = (blockIdx.x * blockDim.x + threadIdx.x) >> 6;
    const int lane  = threadIdx.x & 63;
    if (gwave >= T * B) return;

    const int t = gwave / B;
    const int b = gwave - t * B;

    const int* offs = offsets + t * B;
    const int start = offs[b];
    const int end   = (b == B - 1) ? N : offs[b + 1];

    const int*   idx   = indices + t * N;
    const float* table = tables + (long long)t * V * D;

    const int rg = lane >> 4;   // row group 0..3
    const int c  = lane & 15;   // float4 chunk 0..15 (covers dims [4c,4c+4))

    float4 acc = make_float4(0.f, 0.f, 0.f, 0.f);
    for (int i = start + rg; i < end; i += 4) {
        const int row = idx[i];
        const float4 v =
            *((const float4*)(table + (long long)row * D) + c);
        acc.x += v.x; acc.y += v.y; acc.z += v.z; acc.w += v.w;
    }

    // Sum the 4 row-groups (lanes l, l^16, l^32, l^48 hold the same chunk c).
    acc.x += __shfl_xor(acc.x, 16);
    acc.y += __shfl_xor(acc.y, 16);
    acc.z += __shfl_xor(acc.z, 16);
    acc.w += __shfl_xor(acc.w, 16);
    acc.x += __shfl_xor(acc.x, 32);
    acc.y += __shfl_xor(acc.y, 32);
    acc.z += __shfl_xor(acc.z, 32);
    acc.w += __shfl_xor(acc.w, 32);

    if (rg == 0) {
        float4* dst = (float4*)(out + ((long long)t * B + b) * D) + c;
        *dst = acc;   // empty bags store zeros (harness poisons d_out)
    }
}

extern "C" void kernel_launch(void* const* d_in, const int* in_sizes, int n_in,
                              void* d_out, int out_size, void* d_ws, size_t ws_size,
                              hipStream_t stream) {
    const float* tables  = (const float*)d_in[0];
    const int*   indices = (const int*)d_in[1];
    const int*   offsets = (const int*)d_in[2];
    float*       out     = (float*)d_out;

    const int total_waves = T * B;              // 16384 bags
    const int threads = 256;                    // 4 waves/block
    const int blocks = (total_waves * 64 + threads - 1) / threads;  // 4096
    embbag_kernel<<<blocks, threads, 0, stream>>>(tables, indices, offsets, out);
}

// Round 2
// 25.523 us; speedup vs baseline: 1.5602x; 1.5602x over previous
//
#include <hip/hip_runtime.h>
#include <hip/hip_bf16.h>

// T=4 tables, V=1e6 vocab, D=64 emb dim, B=4096 bags, N=81920 indices/table.
constexpr int T = 4;
constexpr int V = 1000000;
constexpr int D = 64;
constexpr int B = 4096;
constexpr int N = 81920;

// One wave per bag. 4 row-groups x 16 lanes; each lane owns one float4 chunk.
// Manual 4x unroll per row-group: batch 4 idx loads, then 4 independent row
// loads -> 16 rows in flight per wave (vs 4) to hide ~900-cycle HBM latency.
__global__ __launch_bounds__(256) void embbag_kernel(
    const float* __restrict__ tables,
    const int* __restrict__ indices,
    const int* __restrict__ offsets,
    float* __restrict__ out) {
    const int gwave = (blockIdx.x * blockDim.x + threadIdx.x) >> 6;
    const int lane  = threadIdx.x & 63;
    if (gwave >= T * B) return;

    const int t = gwave / B;
    const int b = gwave - t * B;

    const int* offs = offsets + t * B;
    const int start = offs[b];
    const int end   = (b == B - 1) ? N : offs[b + 1];

    const int*   idx   = indices + t * N;
    const float* table = tables + (long long)t * V * D;

    const int rg = lane >> 4;   // row group 0..3
    const int c  = lane & 15;   // float4 chunk (dims [4c, 4c+4))

    float4 acc = make_float4(0.f, 0.f, 0.f, 0.f);

    int i = start + rg;
    // Unrolled-by-4 main loop: rows i, i+4, i+8, i+12 per row-group.
    for (; i + 12 < end; i += 16) {
        const int r0 = idx[i];
        const int r1 = idx[i + 4];
        const int r2 = idx[i + 8];
        const int r3 = idx[i + 12];
        const float4 v0 = *((const float4*)(table + (long long)r0 * D) + c);
        const float4 v1 = *((const float4*)(table + (long long)r1 * D) + c);
        const float4 v2 = *((const float4*)(table + (long long)r2 * D) + c);
        const float4 v3 = *((const float4*)(table + (long long)r3 * D) + c);
        acc.x += v0.x + v1.x + v2.x + v3.x;
        acc.y += v0.y + v1.y + v2.y + v3.y;
        acc.z += v0.z + v1.z + v2.z + v3.z;
        acc.w += v0.w + v1.w + v2.w + v3.w;
    }
    // Tail.
    for (; i < end; i += 4) {
        const int row = idx[i];
        const float4 v = *((const float4*)(table + (long long)row * D) + c);
        acc.x += v.x; acc.y += v.y; acc.z += v.z; acc.w += v.w;
    }

    // Combine the 4 row-groups (lanes l, l^16, l^32, l^48 share chunk c).
    acc.x += __shfl_xor(acc.x, 16);
    acc.y += __shfl_xor(acc.y, 16);
    acc.z += __shfl_xor(acc.z, 16);
    acc.w += __shfl_xor(acc.w, 16);
    acc.x += __shfl_xor(acc.x, 32);
    acc.y += __shfl_xor(acc.y, 32);
    acc.z += __shfl_xor(acc.z, 32);
    acc.w += __shfl_xor(acc.w, 32);

    if (rg == 0) {
        float4* dst = (float4*)(out + ((long long)t * B + b) * D) + c;
        *dst = acc;   // empty bags store zeros (harness poisons d_out)
    }
}

extern "C" void kernel_launch(void* const* d_in, const int* in_sizes, int n_in,
                              void* d_out, int out_size, void* d_ws, size_t ws_size,
                              hipStream_t stream) {
    const float* tables  = (const float*)d_in[0];
    const int*   indices = (const int*)d_in[1];
    const int*   offsets = (const int*)d_in[2];
    float*       out     = (float*)d_out;

    const int total_waves = T * B;              // 16384 bags
    const int threads = 256;                    // 4 waves/block
    const int blocks = (total_waves * 64 + threads - 1) / threads;  // 4096
    embbag_kernel<<<blocks, threads, 0, stream>>>(tables, indices, offsets, out);
}

// Round 3
// 24.760 us; speedup vs baseline: 1.6083x; 1.0308x over previous
//
#include <hip/hip_runtime.h>
#include <hip/hip_bf16.h>

// T=4 tables, V=1e6 vocab, D=64 emb dim, B=4096 bags, N=81920 indices/table.
constexpr int T = 4;
constexpr int V = 1000000;
constexpr int D = 64;
constexpr int B = 4096;
constexpr int N = 81920;

// 2 waves per bag (8 row-groups x 16 lanes), unroll-4 per row-group:
// 32 rows in flight per bag, halved worst-case dependent chain vs R1.
// Cross-wave combine through LDS; lanes 0..15 of the bag's wave 0 store.
__global__ __launch_bounds__(256) void embbag_kernel(
    const float* __restrict__ tables,
    const int* __restrict__ indices,
    const int* __restrict__ offsets,
    float* __restrict__ out) {
    __shared__ float4 part[4][16];   // per-wave partials (1 KB)

    const int wv   = threadIdx.x >> 6;        // wave in block: 0..3
    const int lane = threadIdx.x & 63;
    const int bag_in_block = wv >> 1;         // 0..1
    const int wave_of_bag  = wv & 1;          // 0..1

    const int gbag = blockIdx.x * 2 + bag_in_block;
    const int t = gbag / B;
    const int b = gbag - t * B;

    const int* offs = offsets + t * B;
    const int start = offs[b];
    const int end   = (b == B - 1) ? N : offs[b + 1];

    const int*   idx   = indices + t * N;
    const float* table = tables + (long long)t * V * D;

    const int rg  = lane >> 4;                // row group within wave: 0..3
    const int rg8 = wave_of_bag * 4 + rg;     // row group within bag: 0..7
    const int c   = lane & 15;                // float4 chunk (dims [4c,4c+4))

    float4 acc = make_float4(0.f, 0.f, 0.f, 0.f);

    int i = start + rg8;
    // Unroll-4 main loop: rows i, i+8, i+16, i+24 per row-group.
    for (; i + 24 < end; i += 32) {
        const int r0 = idx[i];
        const int r1 = idx[i + 8];
        const int r2 = idx[i + 16];
        const int r3 = idx[i + 24];
        const float4 v0 = *((const float4*)(table + (long long)r0 * D) + c);
        const float4 v1 = *((const float4*)(table + (long long)r1 * D) + c);
        const float4 v2 = *((const float4*)(table + (long long)r2 * D) + c);
        const float4 v3 = *((const float4*)(table + (long long)r3 * D) + c);
        acc.x += v0.x + v1.x + v2.x + v3.x;
        acc.y += v0.y + v1.y + v2.y + v3.y;
        acc.z += v0.z + v1.z + v2.z + v3.z;
        acc.w += v0.w + v1.w + v2.w + v3.w;
    }
    // Tail.
    for (; i < end; i += 8) {
        const int row = idx[i];
        const float4 v = *((const float4*)(table + (long long)row * D) + c);
        acc.x += v.x; acc.y += v.y; acc.z += v.z; acc.w += v.w;
    }

    // Reduce the 4 row-groups within the wave (lanes sharing chunk c).
    acc.x += __shfl_xor(acc.x, 16);
    acc.y += __shfl_xor(acc.y, 16);
    acc.z += __shfl_xor(acc.z, 16);
    acc.w += __shfl_xor(acc.w, 16);
    acc.x += __shfl_xor(acc.x, 32);
    acc.y += __shfl_xor(acc.y, 32);
    acc.z += __shfl_xor(acc.z, 32);
    acc.w += __shfl_xor(acc.w, 32);

    // Cross-wave combine via LDS; the bag's wave 0 stores.
    if (rg == 0) part[wv][c] = acc;
    __syncthreads();
    if (wave_of_bag == 0 && rg == 0) {
        const float4 p = part[wv | 1][c];
        acc.x += p.x; acc.y += p.y; acc.z += p.z; acc.w += p.w;
        float4* dst = (float4*)(out + ((long long)t * B + b) * D) + c;
        *dst = acc;   // empty bags store zeros (harness poisons d_out)
    }
}

extern "C" void kernel_launch(void* const* d_in, const int* in_sizes, int n_in,
                              void* d_out, int out_size, void* d_ws, size_t ws_size,
                              hipStream_t stream) {
    const float* tables  = (const float*)d_in[0];
    const int*   indices = (const int*)d_in[1];
    const int*   offsets = (const int*)d_in[2];
    float*       out     = (float*)d_out;

    const int blocks = (T * B) / 2;   // 2 bags per 256-thread block -> 8192
    embbag_kernel<<<blocks, 256, 0, stream>>>(tables, indices, offsets, out);
}

// Round 4
// 24.732 us; speedup vs baseline: 1.6101x; 1.0011x over previous
//
#include <hip/hip_runtime.h>
#include <hip/hip_bf16.h>

// T=4 tables, V=1e6 vocab, D=64 emb dim, B=4096 bags, N=81920 indices/table.
constexpr int T = 4;
constexpr int V = 1000000;
constexpr int D = 64;
constexpr int B = 4096;
constexpr int N = 81920;

// 2 waves per bag (8 row-groups x 16 lanes), unroll-4, with the index loads
// software-pipelined one stage ahead: iter k+1's idx loads are issued BEFORE
// iter k's row loads, so the per-iter dependent chain is one HBM round-trip
// (row load) instead of two (idx -> row).
__global__ __launch_bounds__(256) void embbag_kernel(
    const float* __restrict__ tables,
    const int* __restrict__ indices,
    const int* __restrict__ offsets,
    float* __restrict__ out) {
    __shared__ float4 part[4][16];   // per-wave partials (1 KB)

    const int wv   = threadIdx.x >> 6;        // wave in block: 0..3
    const int lane = threadIdx.x & 63;
    const int bag_in_block = wv >> 1;         // 0..1
    const int wave_of_bag  = wv & 1;          // 0..1

    const int gbag = blockIdx.x * 2 + bag_in_block;
    const int t = gbag / B;
    const int b = gbag - t * B;

    const int* offs = offsets + t * B;
    const int start = offs[b];
    const int end   = (b == B - 1) ? N : offs[b + 1];

    const int*  idx   = indices + t * N;
    const char* table = (const char*)(tables + (long long)t * V * D);

    const int rg  = lane >> 4;                // row group within wave: 0..3
    const int rg8 = wave_of_bag * 4 + rg;     // row group within bag: 0..7
    const int c   = lane & 15;                // float4 chunk (dims [4c,4c+4))

    float4 acc = make_float4(0.f, 0.f, 0.f, 0.f);

    int i = start + rg8;
    if (i + 24 < end) {
        // Prologue: first 4 indices.
        int r0 = idx[i], r1 = idx[i + 8], r2 = idx[i + 16], r3 = idx[i + 24];
        const int q = N - 1;
        for (;;) {
            const int ni = i + 32;
            const bool more = (ni + 24 < end);
            // Prefetch next iteration's indices (clamped, always in-bounds).
            const int n0 = idx[ni      < q ? ni      : q];
            const int n1 = idx[ni + 8  < q ? ni + 8  : q];
            const int n2 = idx[ni + 16 < q ? ni + 16 : q];
            const int n3 = idx[ni + 24 < q ? ni + 24 : q];
            const float4 v0 = *((const float4*)(table + ((long long)r0 << 8)) + c);
            const float4 v1 = *((const float4*)(table + ((long long)r1 << 8)) + c);
            const float4 v2 = *((const float4*)(table + ((long long)r2 << 8)) + c);
            const float4 v3 = *((const float4*)(table + ((long long)r3 << 8)) + c);
            acc.x += v0.x + v1.x + v2.x + v3.x;
            acc.y += v0.y + v1.y + v2.y + v3.y;
            acc.z += v0.z + v1.z + v2.z + v3.z;
            acc.w += v0.w + v1.w + v2.w + v3.w;
            i = ni;
            if (!more) break;
            r0 = n0; r1 = n1; r2 = n2; r3 = n3;
        }
    }
    // Tail (<4 rows per row-group remain).
    for (; i < end; i += 8) {
        const int row = idx[i];
        const float4 v = *((const float4*)(table + ((long long)row << 8)) + c);
        acc.x += v.x; acc.y += v.y; acc.z += v.z; acc.w += v.w;
    }

    // Reduce the 4 row-groups within the wave (lanes sharing chunk c).
    acc.x += __shfl_xor(acc.x, 16);
    acc.y += __shfl_xor(acc.y, 16);
    acc.z += __shfl_xor(acc.z, 16);
    acc.w += __shfl_xor(acc.w, 16);
    acc.x += __shfl_xor(acc.x, 32);
    acc.y += __shfl_xor(acc.y, 32);
    acc.z += __shfl_xor(acc.z, 32);
    acc.w += __shfl_xor(acc.w, 32);

    // Cross-wave combine via LDS; the bag's wave 0 stores.
    if (rg == 0) part[wv][c] = acc;
    __syncthreads();
    if (wave_of_bag == 0 && rg == 0) {
        const float4 p = part[wv | 1][c];
        acc.x += p.x; acc.y += p.y; acc.z += p.z; acc.w += p.w;
        float4* dst = (float4*)(out + ((long long)t * B + b) * D) + c;
        *dst = acc;   // empty bags store zeros (harness poisons d_out)
    }
}

extern "C" void kernel_launch(void* const* d_in, const int* in_sizes, int n_in,
                              void* d_out, int out_size, void* d_ws, size_t ws_size,
                              hipStream_t stream) {
    const float* tables  = (const float*)d_in[0];
    const int*   indices = (const int*)d_in[1];
    const int*   offsets = (const int*)d_in[2];
    float*       out     = (float*)d_out;

    const int blocks = (T * B) / 2;   // 2 bags per 256-thread block -> 8192
    embbag_kernel<<<blocks, 256, 0, stream>>>(tables, indices, offsets, out);
}